// Round 3
// baseline (631.021 us; speedup 1.0000x reference)
//
#include <hip/hip_runtime.h>
#include <hip/hip_cooperative_groups.h>
#include <math.h>

namespace cg = cooperative_groups;

#define BB 4096
#define CC 1000
#define DD 1024
#define NROWBLK 1024      // blocks 0..1023 process 4 feature rows each; block 1024 sorts
#define SCALEF 100.0f

__device__ inline float wave_reduce(float v) {
#pragma unroll
    for (int off = 32; off > 0; off >>= 1) v += __shfl_down(v, off);
    return v;
}

__global__ __launch_bounds__(256) void k_all(const float* __restrict__ feature,
                                             const float* __restrict__ query,
                                             const int* __restrict__ target,
                                             float* __restrict__ partialT,  // [DD][NROWBLK]
                                             float* __restrict__ S,
                                             int* __restrict__ order,
                                             float* __restrict__ p,
                                             float* __restrict__ nnval,
                                             float* __restrict__ out) {
    cg::grid_group grid = cg::this_grid();

    __shared__ float red[4][3];
    __shared__ float s_rn;
    __shared__ unsigned short s_tgt[BB];   // 8KB
    __shared__ unsigned short s_ord[BB];   // 8KB
    __shared__ int s_cnt[1024];            // 4KB
    __shared__ int s_start[1024];          // 4KB
    __shared__ int s_wsum[4];
    __shared__ float fred[4];

    int tid = threadIdx.x;
    int bid = blockIdx.x;
    int lane = tid & 63, wv = tid >> 6;

    // ================= Phase 1: rows (+ concurrent sort) =================
    if (bid == NROWBLK) {
        // ---- stable counting sort of target into order[] ----
        for (int i = tid; i < 1024; i += 256) s_cnt[i] = 0;
        for (int i = tid; i < BB; i += 256) s_tgt[i] = (unsigned short)target[i];
        __syncthreads();
        for (int i = tid; i < BB; i += 256) atomicAdd(&s_cnt[s_tgt[i]], 1);
        __syncthreads();
        int b4 = tid * 4;
        int c0 = s_cnt[b4], c1 = s_cnt[b4 + 1], c2 = s_cnt[b4 + 2], c3 = s_cnt[b4 + 3];
        int tot = c0 + c1 + c2 + c3;
        int inc = tot;
#pragma unroll
        for (int off = 1; off < 64; off <<= 1) {
            int t = __shfl_up(inc, off);
            if (lane >= off) inc += t;
        }
        if (lane == 63) s_wsum[wv] = inc;
        __syncthreads();
        int wpre = 0;
        for (int w = 0; w < wv; ++w) wpre += s_wsum[w];
        int excl = wpre + inc - tot;
        s_start[b4] = excl;
        s_start[b4 + 1] = excl + c0;
        s_start[b4 + 2] = excl + c0 + c1;
        s_start[b4 + 3] = excl + c0 + c1 + c2;
        s_cnt[b4] = 0; s_cnt[b4 + 1] = 0; s_cnt[b4 + 2] = 0; s_cnt[b4 + 3] = 0;
        __syncthreads();
        for (int i = tid; i < BB; i += 256) {
            int c = s_tgt[i];
            int j = atomicAdd(&s_cnt[c], 1);
            s_ord[s_start[c] + j] = (unsigned short)i;
        }
        __syncthreads();
        for (int c = tid; c < 1024; c += 256) {
            int s = s_start[c], n = s_cnt[c];
            for (int a = 1; a < n; ++a) {
                unsigned short key = s_ord[s + a];
                int j = a - 1;
                while (j >= 0 && s_ord[s + j] > key) { s_ord[s + j + 1] = s_ord[s + j]; --j; }
                s_ord[s + j + 1] = key;
            }
        }
        __syncthreads();
        for (int i = tid; i < BB; i += 256) order[i] = (int)s_ord[i];
    } else {
        // ---- 4 feature rows: p[b] and partial column-sum ----
        int b0 = bid * 4;
        float4 acc = make_float4(0.f, 0.f, 0.f, 0.f);
        for (int r = 0; r < 4; ++r) {
            int b = b0 + r;
            int tb = target[b];
            float4 x = ((const float4*)(feature + (size_t)b * DD))[tid];
            float4 q = ((const float4*)(query + (size_t)tb * DD))[tid];
            float nf = x.x * x.x + x.y * x.y + x.z * x.z + x.w * x.w;
            float nq = q.x * q.x + q.y * q.y + q.z * q.z + q.w * q.w;
            float dt = x.x * q.x + x.y * q.y + x.z * q.z + x.w * q.w;
            nf = wave_reduce(nf);
            nq = wave_reduce(nq);
            dt = wave_reduce(dt);
            if (lane == 0) { red[wv][0] = nf; red[wv][1] = nq; red[wv][2] = dt; }
            __syncthreads();
            if (tid == 0) {
                float a = red[0][0] + red[1][0] + red[2][0] + red[3][0];
                float bq = red[0][1] + red[1][1] + red[2][1] + red[3][1];
                float c = red[0][2] + red[1][2] + red[2][2] + red[3][2];
                float rn = rsqrtf(a);
                s_rn = rn;
                p[b] = c * rn * rsqrtf(bq);
            }
            __syncthreads();
            float rn = s_rn;
            acc.x += x.x * rn; acc.y += x.y * rn; acc.z += x.z * rn; acc.w += x.w * rn;
        }
        // transposed write: column `bid`, dims 4tid..4tid+3
        int d0 = tid * 4;
        partialT[(size_t)(d0 + 0) * NROWBLK + bid] = acc.x;
        partialT[(size_t)(d0 + 1) * NROWBLK + bid] = acc.y;
        partialT[(size_t)(d0 + 2) * NROWBLK + bid] = acc.z;
        partialT[(size_t)(d0 + 3) * NROWBLK + bid] = acc.w;
    }
    __threadfence();
    grid.sync();

    // ================= Phase 2: S[d] = sum of partialT row d =================
    if (bid < DD) {
        float4 v = ((const float4*)(partialT + (size_t)bid * NROWBLK))[tid];
        float s = v.x + v.y + v.z + v.w;
        s = wave_reduce(s);
        if (lane == 0) fred[wv] = s;
        __syncthreads();
        if (tid == 0) S[bid] = fred[0] + fred[1] + fred[2] + fred[3];
    }
    __threadfence();
    grid.sync();

    // ================= Phase 3: nnval[c] = (10/B) * (S . q_c)/||q_c|| =================
    if (bid < CC) {
        float4 q = ((const float4*)(query + (size_t)bid * DD))[tid];
        float4 s4 = ((const float4*)S)[tid];
        float nq = q.x * q.x + q.y * q.y + q.z * q.z + q.w * q.w;
        float dt = q.x * s4.x + q.y * s4.y + q.z * s4.z + q.w * s4.w;
        nq = wave_reduce(nq);
        dt = wave_reduce(dt);
        if (lane == 0) { red[wv][0] = nq; red[wv][1] = dt; }
        __syncthreads();
        if (tid == 0) {
            float a = red[0][0] + red[1][0] + red[2][0] + red[3][0];
            float b = red[0][1] + red[1][1] + red[2][1] + red[3][1];
            nnval[bid] = (10.0f / (float)BB) * b * rsqrtf(a);
        }
    }
    __threadfence();
    grid.sync();

    // ================= Phase 4: loss =================
    if (bid == 0) {
        float acc = 0.f;
        for (int i = tid; i < BB; i += 256) {
            int b = order[i];
            float d = SCALEF * (nnval[target[i]] - p[b]);
            acc += (d > 0.f) ? (d + log1pf(expf(-d))) : log1pf(expf(d));
        }
        acc = wave_reduce(acc);
        if (lane == 0) fred[wv] = acc;
        __syncthreads();
        if (tid == 0) out[0] = (fred[0] + fred[1] + fred[2] + fred[3]) / (float)BB;
    }
}

extern "C" void kernel_launch(void* const* d_in, const int* in_sizes, int n_in,
                              void* d_out, int out_size, void* d_ws, size_t ws_size,
                              hipStream_t stream) {
    const float* feature = (const float*)d_in[0];
    const float* query   = (const float*)d_in[1];
    const int*   target  = (const int*)d_in[2];
    float* out = (float*)d_out;
    float* ws  = (float*)d_ws;

    float* p        = ws;                      // 4096
    float* S        = ws + 4096;               // 1024
    float* nnval    = ws + 5120;               // 1024 (1000 used)
    int*   order    = (int*)(ws + 6144);       // 4096 ints
    float* partialT = ws + 10240;              // DD*NROWBLK = 4M floats

    void* args[] = {(void*)&feature, (void*)&query, (void*)&target,
                    (void*)&partialT, (void*)&S, (void*)&order,
                    (void*)&p, (void*)&nnval, (void*)&out};
    hipLaunchCooperativeKernel((const void*)k_all, dim3(NROWBLK + 1), dim3(256),
                               args, 0, stream);
}

// Round 4
// 63.441 us; speedup vs baseline: 9.9466x; 9.9466x over previous
//
#include <hip/hip_runtime.h>
#include <math.h>

#define BB 4096
#define CC 1000
#define DD 1024
#define NRB 512           // row blocks; 8 rows each (2 rows per wave)
#define SCALEF 100.0f

__device__ inline float wred(float v) {
#pragma unroll
    for (int o = 32; o > 0; o >>= 1) v += __shfl_down(v, o);
    return v;
}

__device__ inline float dot4(float4 a, float4 b) {
    return a.x * b.x + a.y * b.y + a.z * b.z + a.w * b.w;
}

// K1: blocks 0..NRB-1: per-row 1/||f||, p[b]=cos(f_b,q_{t_b}); block-partial
// normalized column sums atomicAdd'ed into S (S pre-zeroed by memset).
// Block NRB: stable counting sort of target -> order, starts, cnts.
__global__ __launch_bounds__(256) void k1(const float* __restrict__ feature,
                                          const float* __restrict__ query,
                                          const int* __restrict__ target,
                                          float* __restrict__ S,
                                          float* __restrict__ p,
                                          int* __restrict__ order,
                                          int* __restrict__ startsg,
                                          int* __restrict__ cntsg) {
    __shared__ float s_accW[4][DD];        // 16KB, per-wave partial S
    __shared__ unsigned short s_tgt[BB];   // 8KB  (sort block only)
    __shared__ unsigned short s_ord[BB];   // 8KB
    __shared__ int s_cnt[1024];            // 4KB
    __shared__ int s_start[1024];          // 4KB
    __shared__ int s_wsum[4];

    int tid = threadIdx.x, lane = tid & 63, wv = tid >> 6, bid = blockIdx.x;

    if (bid == NRB) {
        // ---- stable counting sort ----
        for (int i = tid; i < 1024; i += 256) s_cnt[i] = 0;
        for (int i = tid; i < BB; i += 256) s_tgt[i] = (unsigned short)target[i];
        __syncthreads();
        for (int i = tid; i < BB; i += 256) atomicAdd(&s_cnt[s_tgt[i]], 1);
        __syncthreads();
        int b4 = tid * 4;
        int c0 = s_cnt[b4], c1 = s_cnt[b4 + 1], c2 = s_cnt[b4 + 2], c3 = s_cnt[b4 + 3];
        int tot = c0 + c1 + c2 + c3;
        int inc = tot;
#pragma unroll
        for (int off = 1; off < 64; off <<= 1) {
            int t = __shfl_up(inc, off);
            if (lane >= off) inc += t;
        }
        if (lane == 63) s_wsum[wv] = inc;
        __syncthreads();
        int wpre = 0;
        for (int w = 0; w < wv; ++w) wpre += s_wsum[w];
        int excl = wpre + inc - tot;
        s_start[b4] = excl;
        s_start[b4 + 1] = excl + c0;
        s_start[b4 + 2] = excl + c0 + c1;
        s_start[b4 + 3] = excl + c0 + c1 + c2;
        s_cnt[b4] = 0; s_cnt[b4 + 1] = 0; s_cnt[b4 + 2] = 0; s_cnt[b4 + 3] = 0;
        __syncthreads();
        for (int i = tid; i < BB; i += 256) {
            int c = s_tgt[i];
            int j = atomicAdd(&s_cnt[c], 1);
            s_ord[s_start[c] + j] = (unsigned short)i;
        }
        __syncthreads();
        for (int c = tid; c < 1024; c += 256) {
            int s = s_start[c], n = s_cnt[c];
            for (int a = 1; a < n; ++a) {
                unsigned short key = s_ord[s + a];
                int j = a - 1;
                while (j >= 0 && s_ord[s + j] > key) { s_ord[s + j + 1] = s_ord[s + j]; --j; }
                s_ord[s + j + 1] = key;
            }
        }
        __syncthreads();
        for (int i = tid; i < BB; i += 256) order[i] = (int)s_ord[i];
        for (int c = tid; c < 1024; c += 256) { startsg[c] = s_start[c]; cntsg[c] = s_cnt[c]; }
        return;
    }

    // ---- row blocks: each wave handles 2 full rows, no block syncs in row path ----
    float4 acc[4];
#pragma unroll
    for (int k = 0; k < 4; ++k) acc[k] = make_float4(0.f, 0.f, 0.f, 0.f);
    int b0 = bid * 8 + wv * 2;
#pragma unroll
    for (int r = 0; r < 2; ++r) {
        int b = b0 + r;
        int tb = target[b];
        const float4* fr = (const float4*)(feature + (size_t)b * DD);
        const float4* qr = (const float4*)(query + (size_t)tb * DD);
        float4 x[4], q[4];
#pragma unroll
        for (int k = 0; k < 4; ++k) { x[k] = fr[lane + 64 * k]; q[k] = qr[lane + 64 * k]; }
        float nf = 0.f, nq = 0.f, dt = 0.f;
#pragma unroll
        for (int k = 0; k < 4; ++k) {
            nf += dot4(x[k], x[k]);
            nq += dot4(q[k], q[k]);
            dt += dot4(x[k], q[k]);
        }
        nf = wred(nf); nq = wred(nq); dt = wred(dt);
        nf = __shfl(nf, 0); nq = __shfl(nq, 0); dt = __shfl(dt, 0);
        float rn = rsqrtf(nf);
        if (lane == 0) p[b] = dt * rn * rsqrtf(nq);
#pragma unroll
        for (int k = 0; k < 4; ++k) {
            acc[k].x += x[k].x * rn; acc[k].y += x[k].y * rn;
            acc[k].z += x[k].z * rn; acc[k].w += x[k].w * rn;
        }
    }
#pragma unroll
    for (int k = 0; k < 4; ++k)
        ((float4*)&s_accW[wv][0])[lane + 64 * k] = acc[k];
    __syncthreads();
    for (int d = tid; d < DD; d += 256) {
        float v = s_accW[0][d] + s_accW[1][d] + s_accW[2][d] + s_accW[3][d];
        atomicAdd(&S[d], v);
    }
}

// K2: block c: nnval[c] = (10/B)*(S.q_c)/||q_c|| (in-register), then loss terms
// of class-c segment; last finished block writes out = acc/B.
__global__ __launch_bounds__(256) void k2(const float* __restrict__ query,
                                          const float* __restrict__ S,
                                          const float* __restrict__ p,
                                          const int* __restrict__ order,
                                          const int* __restrict__ startsg,
                                          const int* __restrict__ cntsg,
                                          float* __restrict__ acc,
                                          unsigned int* __restrict__ counter,
                                          float* __restrict__ out) {
    __shared__ float red[4][2];
    __shared__ float red2[4];
    int c = blockIdx.x, tid = threadIdx.x, lane = tid & 63, wv = tid >> 6;

    float4 q = ((const float4*)(query + (size_t)c * DD))[tid];
    float4 s = ((const float4*)S)[tid];
    float nq = dot4(q, q);
    float dt = dot4(q, s);
    nq = wred(nq); dt = wred(dt);
    if (lane == 0) { red[wv][0] = nq; red[wv][1] = dt; }
    __syncthreads();
    nq = red[0][0] + red[1][0] + red[2][0] + red[3][0];
    dt = red[0][1] + red[1][1] + red[2][1] + red[3][1];
    float nn = (10.0f / (float)BB) * dt * rsqrtf(nq);

    int s0 = startsg[c], n = cntsg[c];
    float part = 0.f;
    for (int j = tid; j < n; j += 256) {
        int i = order[s0 + j];       // sample index with target[i] == c
        int oi = order[i];           // perm[i]
        float d = SCALEF * (nn - p[oi]);
        part += (d > 0.f) ? (d + log1pf(expf(-d))) : log1pf(expf(d));
    }
    part = wred(part);
    if (lane == 0) red2[wv] = part;
    __syncthreads();
    if (tid == 0) {
        float tot = red2[0] + red2[1] + red2[2] + red2[3];
        atomicAdd(acc, tot);
        __threadfence();
        unsigned int old = atomicAdd(counter, 1u);
        if (old == (unsigned int)(CC - 1)) {
            __threadfence();
            float a = atomicAdd(acc, 0.0f);   // read fully-accumulated value
            out[0] = a / (float)BB;
        }
    }
}

extern "C" void kernel_launch(void* const* d_in, const int* in_sizes, int n_in,
                              void* d_out, int out_size, void* d_ws, size_t ws_size,
                              hipStream_t stream) {
    const float* feature = (const float*)d_in[0];
    const float* query   = (const float*)d_in[1];
    const int*   target  = (const int*)d_in[2];
    float* out = (float*)d_out;
    float* ws  = (float*)d_ws;

    float*        S       = ws;                         // 1024 floats
    float*        acc     = ws + 1024;                  // 1 float
    unsigned int* counter = (unsigned int*)(ws + 1025); // 1 uint
    float*        p       = ws + 2048;                  // 4096 floats
    int*          order   = (int*)(ws + 6144);          // 4096 ints
    int*          startsg = (int*)(ws + 10240);         // 1024 ints
    int*          cntsg   = (int*)(ws + 11264);         // 1024 ints

    hipMemsetAsync(ws, 0, 4112, stream);  // S + acc + counter
    k1<<<NRB + 1, 256, 0, stream>>>(feature, query, target, S, p, order, startsg, cntsg);
    k2<<<CC, 256, 0, stream>>>(query, S, p, order, startsg, cntsg, acc, counter, out);
}